// Round 1
// baseline (282.388 us; speedup 1.0000x reference)
//
#include <hip/hip_runtime.h>
#include <hip/hip_cooperative_groups.h>

namespace cg = cooperative_groups;

// DicepolyTopk fused: dice + mean of top-10% poly1-BCE over N=16.7M fp32.
// R5: single cooperative kernel (was 6 dispatches, ~80us of gaps + single-block
// kernel latency). Phases: zero-ws -> scan1(dice sums + L1 hist) -> select1
// (block 0) -> scan2(sum>b1 + L2 hist in bucket b1) -> select2+finalize
// (block 0), separated by grid.sync(). Scan loops are software-pipelined
// (2x float4 per array per stage, next stage prefetched -> 64B in flight/wave)
// and use 512-thread blocks: LDS ~35KB no longer caps threads/CU; VGPR<=128
// via __launch_bounds__(512,4) -> 16 waves/CU, 2 blocks/CU co-resident.
// Grid sized from the occupancy API so cooperative launch cannot oversubscribe.

#define NBINS 4096
#define NREP1 8
#define NREP2 4
#define BLK 512
#define MAXG 1024
#define POLY_EPS 3.1f
#define LN2F 0.69314718056f

struct Ctl {
  unsigned int b1;  // L1 bucket containing the k-th largest value
  unsigned int r;   // k - count(strictly greater L1 buckets)
};

// bce in log2 domain: a2=log2(p), b2=log2(1-p); bce2 = -(b2 + t*(a2-b2))
// bce = bce2*ln2 ; pt = 2^(-bce2) ; poly1 = bce + (1-pt)*eps, clamped >= 0.
__device__ __forceinline__ float poly1_val(float p, float t) {
  float a2 = __builtin_amdgcn_logf(p);         // v_log_f32: log2(p)
  float b2 = __builtin_amdgcn_logf(1.0f - p);  // log2(1-p)
  float bce2 = -(b2 + t * (a2 - b2));
  float pt = __builtin_amdgcn_exp2f(-bce2);    // v_exp_f32: 2^(-bce2)
  float v = bce2 * LN2F + (1.0f - pt) * POLY_EPS;
  return v > 0.0f ? v : 0.0f;
}

__global__ void __launch_bounds__(BLK, 4) fused_kernel(
    const float* __restrict__ preds, const float* __restrict__ gts,
    long long n, Ctl* __restrict__ ctl, double* __restrict__ blockSums,
    double* __restrict__ blockSgt, unsigned int* __restrict__ hist1R,
    unsigned int* __restrict__ hist2R, float* __restrict__ sum2R,
    unsigned int K, float* __restrict__ out) {
  cg::grid_group gg = cg::this_grid();

  __shared__ unsigned int h[NBINS];
  __shared__ float s[NBINS];
  __shared__ unsigned int chunk[BLK];
  __shared__ double wred[8][4];
  __shared__ double redsA[8], redsB[8], redsC[8];
  __shared__ unsigned int sb2, sr2;

  const int t = threadIdx.x;
  const long long NT = (long long)gridDim.x * BLK;
  const long long gtid = (long long)blockIdx.x * BLK + t;
  const long long n8 = n >> 3;  // groups of 8 floats (2x float4)
  const float4* p4 = (const float4*)preds;
  const float4* t4 = (const float4*)gts;

  // ---------------- phase 0: zero replicas (hist1R..sum2R contiguous) ------
  {
    const long long zwords = (long long)(NREP1 + 2 * NREP2) * NBINS;
    for (long long i = gtid; i < zwords; i += NT) hist1R[i] = 0u;
    for (int i = t; i < NBINS; i += BLK) h[i] = 0u;
  }
  gg.sync();

  // ---------------- phase 1: dice sums + L1 histogram ----------------------
  float fI = 0.f, fSp = 0.f, fSt = 0.f;
#define PROC1(pp, tt)                                  \
  do {                                                 \
    float _p = (pp), _t = (tt);                        \
    fI += _p * _t;                                     \
    fSp += _p;                                         \
    fSt += _t;                                         \
    float _v = poly1_val(_p, _t);                      \
    atomicAdd(&h[__float_as_uint(_v) >> 19], 1u);      \
  } while (0)
  {
    long long i = gtid;
    bool have = (i < n8);
    float4 pa, pb, ta, tb;
    if (have) {
      long long j = i << 1;
      pa = p4[j]; pb = p4[j + 1]; ta = t4[j]; tb = t4[j + 1];
    }
    while (have) {
      long long ni = i + NT;
      bool hn = (ni < n8);
      float4 qa, qb, ua, ub;
      if (hn) {  // issue next stage's 64B before processing current stage
        long long j = ni << 1;
        qa = p4[j]; qb = p4[j + 1]; ua = t4[j]; ub = t4[j + 1];
      }
      PROC1(pa.x, ta.x); PROC1(pa.y, ta.y); PROC1(pa.z, ta.z); PROC1(pa.w, ta.w);
      PROC1(pb.x, tb.x); PROC1(pb.y, tb.y); PROC1(pb.z, tb.z); PROC1(pb.w, tb.w);
      if (hn) { pa = qa; pb = qb; ta = ua; tb = ub; }
      i = ni;
      have = hn;
    }
    for (long long e = (n8 << 3) + gtid; e < n; e += NT) PROC1(preds[e], gts[e]);
  }
#undef PROC1
  {
    double dI = fI, dSp = fSp, dSt = fSt;
#pragma unroll
    for (int off = 32; off; off >>= 1) {
      dI += __shfl_down(dI, off, 64);
      dSp += __shfl_down(dSp, off, 64);
      dSt += __shfl_down(dSt, off, 64);
    }
    if ((t & 63) == 0) { int w = t >> 6; wred[w][0] = dI; wred[w][1] = dSp; wred[w][2] = dSt; }
    __syncthreads();  // also orders h[] for the flush below
    if (t == 0) {
      double a = 0, b = 0, c = 0;
#pragma unroll
      for (int w = 0; w < 8; ++w) { a += wred[w][0]; b += wred[w][1]; c += wred[w][2]; }
      // device-scope atomic stores: coherent across XCDs before grid.sync
      atomicExch((unsigned long long*)&blockSums[blockIdx.x * 3 + 0],
                 (unsigned long long)__double_as_longlong(a));
      atomicExch((unsigned long long*)&blockSums[blockIdx.x * 3 + 1],
                 (unsigned long long)__double_as_longlong(b));
      atomicExch((unsigned long long*)&blockSums[blockIdx.x * 3 + 2],
                 (unsigned long long)__double_as_longlong(c));
    }
    unsigned int* dst = hist1R + (size_t)(blockIdx.x & (NREP1 - 1)) * NBINS;
    for (int i = t; i < NBINS; i += BLK) {
      unsigned c2 = h[i];
      if (c2) atomicAdd(&dst[i], c2);
    }
  }
  gg.sync();

  // ---------------- select1 (block 0): find L1 bucket of k-th value --------
  if (blockIdx.x == 0) {
    unsigned hl[8];
    unsigned c = 0;
#pragma unroll
    for (int j = 0; j < 8; ++j) {
      unsigned ssum = 0;
#pragma unroll
      for (int rp = 0; rp < NREP1; ++rp) ssum += hist1R[(size_t)rp * NBINS + t * 8 + j];
      hl[j] = ssum;
      c += ssum;
    }
    chunk[t] = c;
    __syncthreads();
    for (int off = 1; off < BLK; off <<= 1) {  // suffix scan over 512 threads
      unsigned add = (t + off < BLK) ? chunk[t + off] : 0u;
      __syncthreads();
      chunk[t] += add;
      __syncthreads();
    }
    unsigned above = (t < BLK - 1) ? chunk[t + 1] : 0u;
    unsigned cum = above;
    for (int j = 7; j >= 0; --j) {
      unsigned nc = cum + hl[j];
      if (cum < K && nc >= K) {  // exactly one (t,j) globally satisfies this
        atomicExch(&ctl->b1, (unsigned)(t * 8 + j));
        atomicExch(&ctl->r, K - cum);
      }
      cum = nc;
    }
  }
  gg.sync();

  // ---------------- phase 2: sum above b1 + refine within b1 ---------------
  {
    const unsigned b1v = ctl->b1;
    for (int i = t; i < NBINS; i += BLK) { h[i] = 0u; s[i] = 0.f; }
    __syncthreads();
    double sgt = 0.0;
#define PROC2(pp, tt)                                   \
  do {                                                  \
    float _v = poly1_val((pp), (tt));                   \
    unsigned _u = __float_as_uint(_v);                  \
    unsigned _b = _u >> 19;                             \
    if (_b > b1v) {                                     \
      sgt += (double)_v;                                \
    } else if (_b == b1v) {                             \
      unsigned _k = (_u >> 7) & 0xFFFu;                 \
      atomicAdd(&h[_k], 1u);                            \
      atomicAdd(&s[_k], _v);                            \
    }                                                   \
  } while (0)
    {
      long long i = gtid;
      bool have = (i < n8);
      float4 pa, pb, ta, tb;
      if (have) {
        long long j = i << 1;
        pa = p4[j]; pb = p4[j + 1]; ta = t4[j]; tb = t4[j + 1];
      }
      while (have) {
        long long ni = i + NT;
        bool hn = (ni < n8);
        float4 qa, qb, ua, ub;
        if (hn) {
          long long j = ni << 1;
          qa = p4[j]; qb = p4[j + 1]; ua = t4[j]; ub = t4[j + 1];
        }
        PROC2(pa.x, ta.x); PROC2(pa.y, ta.y); PROC2(pa.z, ta.z); PROC2(pa.w, ta.w);
        PROC2(pb.x, tb.x); PROC2(pb.y, tb.y); PROC2(pb.z, tb.z); PROC2(pb.w, tb.w);
        if (hn) { pa = qa; pb = qb; ta = ua; tb = ub; }
        i = ni;
        have = hn;
      }
      for (long long e = (n8 << 3) + gtid; e < n; e += NT) PROC2(preds[e], gts[e]);
    }
#undef PROC2
#pragma unroll
    for (int off = 32; off; off >>= 1) sgt += __shfl_down(sgt, off, 64);
    if ((t & 63) == 0) wred[t >> 6][0] = sgt;
    __syncthreads();
    if (t == 0) {
      double sg = 0;
#pragma unroll
      for (int w = 0; w < 8; ++w) sg += wred[w][0];
      atomicExch((unsigned long long*)&blockSgt[blockIdx.x],
                 (unsigned long long)__double_as_longlong(sg));
    }
    unsigned int* hd = hist2R + (size_t)(blockIdx.x & (NREP2 - 1)) * NBINS;
    float* sd = sum2R + (size_t)(blockIdx.x & (NREP2 - 1)) * NBINS;
    for (int i = t; i < NBINS; i += BLK) {
      unsigned c2 = h[i];
      if (c2) atomicAdd(&hd[i], c2);
      float sv = s[i];
      if (sv != 0.f) atomicAdd(&sd[i], sv);
    }
  }
  gg.sync();

  // ---------------- select2 + finalize (block 0) ---------------------------
  if (blockIdx.x == 0) {
    const unsigned K2 = ctl->r;  // remaining count needed from bucket b1 (>=1)
    unsigned hl[8];
    float sl[8];
    unsigned c = 0;
#pragma unroll
    for (int j = 0; j < 8; ++j) {
      unsigned hs = 0;
      float ss = 0.f;
#pragma unroll
      for (int rp = 0; rp < NREP2; ++rp) {
        hs += hist2R[(size_t)rp * NBINS + t * 8 + j];
        ss += sum2R[(size_t)rp * NBINS + t * 8 + j];
      }
      hl[j] = hs;
      sl[j] = ss;
      c += hs;
    }
    chunk[t] = c;
    __syncthreads();
    for (int off = 1; off < BLK; off <<= 1) {
      unsigned add = (t + off < BLK) ? chunk[t + off] : 0u;
      __syncthreads();
      chunk[t] += add;
      __syncthreads();
    }
    unsigned above = (t < BLK - 1) ? chunk[t + 1] : 0u;
    unsigned cum = above;
    for (int j = 7; j >= 0; --j) {
      unsigned nc = cum + hl[j];
      if (cum < K2 && nc >= K2) { sb2 = (unsigned)(t * 8 + j); sr2 = K2 - cum; }
      cum = nc;
    }
    __syncthreads();
    const unsigned b2 = sb2, r2 = sr2;
    // exact sum of sub-buckets strictly above b2; b2's own count/sum
    double loc = 0.0, b2s = 0.0, b2c = 0.0;
#pragma unroll
    for (int j = 0; j < 8; ++j) {
      int bin = t * 8 + j;
      if (bin > (int)b2) loc += (double)sl[j];
      if (bin == (int)b2) { b2s = (double)sl[j]; b2c = (double)hl[j]; }
    }
#pragma unroll
    for (int off = 32; off; off >>= 1) {
      loc += __shfl_down(loc, off, 64);
      b2s += __shfl_down(b2s, off, 64);
      b2c += __shfl_down(b2c, off, 64);
    }
    if ((t & 63) == 0) { int w = t >> 6; redsA[w] = loc; redsB[w] = b2s; redsC[w] = b2c; }
    __syncthreads();

    // reduce per-block dice partials + Sgt (all 512 threads of block 0)
    double I = 0, Sp = 0, St = 0, Sg = 0;
    const int g = (int)gridDim.x;
    for (int i = t; i < g; i += BLK) {
      I += blockSums[i * 3 + 0];
      Sp += blockSums[i * 3 + 1];
      St += blockSums[i * 3 + 2];
      Sg += blockSgt[i];
    }
#pragma unroll
    for (int off = 32; off; off >>= 1) {
      I += __shfl_down(I, off, 64);
      Sp += __shfl_down(Sp, off, 64);
      St += __shfl_down(St, off, 64);
      Sg += __shfl_down(Sg, off, 64);
    }
    if ((t & 63) == 0) { int w = t >> 6; wred[w][0] = I; wred[w][1] = Sp; wred[w][2] = St; wred[w][3] = Sg; }
    __syncthreads();
    if (t == 0) {
      double S2 = 0, bs = 0, bc = 0;
#pragma unroll
      for (int w = 0; w < 8; ++w) { S2 += redsA[w]; bs += redsB[w]; bc += redsC[w]; }
      // ties in sub-bucket b2 span < 128 ulps: bin average for r2 remaining
      double topk_extra = S2 + (double)r2 * (bs / bc);
      double tI = 0, tSp = 0, tSt = 0, tSg = 0;
#pragma unroll
      for (int w = 0; w < 8; ++w) {
        tI += wred[w][0]; tSp += wred[w][1]; tSt += wred[w][2]; tSg += wred[w][3];
      }
      double dice = 1.0 - (2.0 * tI + 1.0) / (tSp + tSt + 1.0);
      out[0] = (float)(dice + (tSg + topk_extra) / (double)K);
    }
  }
}

extern "C" void kernel_launch(void* const* d_in, const int* in_sizes, int n_in,
                              void* d_out, int out_size, void* d_ws,
                              size_t ws_size, hipStream_t stream) {
  (void)n_in; (void)out_size; (void)ws_size;
  const float* preds = (const float*)d_in[0];
  const float* gts = (const float*)d_in[1];
  long long n = (long long)in_sizes[0];
  unsigned int K = (unsigned int)(n * 10 / 100);  // matches int(N*10/100)
  float* outp = (float*)d_out;

  char* ws = (char*)d_ws;
  Ctl* ctl = (Ctl*)ws;                                 // @0, pad to 64
  double* blockSums = (double*)(ws + 64);              // MAXG*3*8 = 24576
  double* blockSgt = (double*)(ws + 64 + 24576);       // MAXG*8   = 8192
  unsigned int* hist1R = (unsigned int*)(ws + 32832);  // NREP1*NBINS*4 = 131072
  unsigned int* hist2R = (unsigned int*)(ws + 163904); // NREP2*NBINS*4 = 65536
  float* sum2R = (float*)(ws + 229440);                // 65536 -> end 294976
  // hist1R..sum2R are contiguous: zeroed in-kernel (phase 0), no memset.

  // Grid = co-resident capacity (occupancy API), so cooperative launch is
  // always valid; all phases are grid-stride so any grid size is correct.
  static int s_grid = 0;
  if (s_grid == 0) {
    int nb = 0;
    if (hipOccupancyMaxActiveBlocksPerMultiprocessor(&nb, fused_kernel, BLK, 0) != hipSuccess || nb < 1)
      nb = 1;
    int dev = 0;
    (void)hipGetDevice(&dev);
    int ncu = 0;
    if (hipDeviceGetAttribute(&ncu, hipDeviceAttributeMultiprocessorCount, dev) != hipSuccess || ncu <= 0)
      ncu = 256;
    long long g = (long long)nb * ncu;
    if (g > MAXG) g = MAXG;
    if (g < 1) g = 1;
    s_grid = (int)g;
  }

  void* args[] = {(void*)&preds, (void*)&gts,   (void*)&n,      (void*)&ctl,
                  (void*)&blockSums, (void*)&blockSgt, (void*)&hist1R,
                  (void*)&hist2R, (void*)&sum2R, (void*)&K,      (void*)&outp};
  (void)hipLaunchCooperativeKernel((void*)fused_kernel, dim3(s_grid), dim3(BLK),
                                   args, 0, stream);
}

// Round 2
// 204.295 us; speedup vs baseline: 1.3823x; 1.3823x over previous
//
#include <hip/hip_runtime.h>

// DicepolyTopk: dice loss + mean of top-10% poly1-BCE values over N=16.7M fp32.
// R6: revert cooperative fusion (R5 regressed: launch_bounds(512,4) capped VGPR
// at 64, defeating the load pipeline -> VALUBusy 18.7->7.0%; grid.sync + idle
// single-block phases billed inside one dispatch). Stream-ordered, 4 dispatches:
//   memset(256KB) -> pass1 -> pass2(select1 embedded per-block) -> sel2fin
// Changes vs the 211.8us baseline:
//  - scan loops process 8 elems/iter (2x float4 per array, straight-line) ->
//    64B/thread of loads in flight, no manual prefetch, no reg strangle
//  - pass2 LDS: u16-packed counts (8KB) + f32 sums (16KB) = 25.6KB -> 6
//    blocks/CU (was 33KB -> 4); __launch_bounds__(256,6) (VGPR cap 85)
//  - select1 folded into pass2 (each block computes b1 redundantly from the
//    8 replica histograms, ~128KB L2 reads) and into sel2fin (needs r too)
//  - select2+finalize merged; NREP1 16->8

#define NBINS 4096
#define NREP1 8
#define NREP2 4
#define G1 2048
#define G2 1536
#define POLY_EPS 3.1f
#define LN2F 0.69314718056f

// bce in log2 domain: a2=log2(p), b2=log2(1-p); bce2 = -(b2 + t*(a2-b2))
// bce = bce2*ln2 ; pt = 2^(-bce2) ; poly1 = bce + (1-pt)*eps, clamped >= 0.
__device__ __forceinline__ float poly1_val(float p, float t) {
  float a2 = __builtin_amdgcn_logf(p);         // v_log_f32: log2(p)
  float b2 = __builtin_amdgcn_logf(1.0f - p);  // log2(1-p)
  float bce2 = -(b2 + t * (a2 - b2));
  float pt = __builtin_amdgcn_exp2f(-bce2);    // v_exp_f32: 2^(-bce2)
  float v = bce2 * LN2F + (1.0f - pt) * POLY_EPS;
  return v > 0.0f ? v : 0.0f;
}

// ---------------- pass 1: dice sums + L1 histogram -------------------------
__global__ void __launch_bounds__(256) pass1_kernel(
    const float* __restrict__ preds, const float* __restrict__ gts,
    long long n, double* __restrict__ blockSums,
    unsigned int* __restrict__ hist1R) {
  __shared__ unsigned int h[NBINS];
  __shared__ double wred[4][3];
  for (int i = threadIdx.x; i < NBINS; i += 256) h[i] = 0u;
  __syncthreads();

  double dI = 0.0, dSp = 0.0, dSt = 0.0;
  const long long n8 = n >> 3;
  const float4* p4 = (const float4*)preds;
  const float4* t4 = (const float4*)gts;
  const long long NT = (long long)G1 * 256;
  const long long gtid = (long long)blockIdx.x * 256 + threadIdx.x;

  for (long long i = gtid; i < n8; i += NT) {
    long long j = i << 1;
    float4 pa = p4[j], pb = p4[j + 1];
    float4 ta = t4[j], tb = t4[j + 1];
    float ps[8] = {pa.x, pa.y, pa.z, pa.w, pb.x, pb.y, pb.z, pb.w};
    float ts[8] = {ta.x, ta.y, ta.z, ta.w, tb.x, tb.y, tb.z, tb.w};
#pragma unroll
    for (int e = 0; e < 8; ++e) {
      float pp = ps[e], tt = ts[e];
      dI += (double)(pp * tt);
      dSp += (double)pp;
      dSt += (double)tt;
      float v = poly1_val(pp, tt);
      atomicAdd(&h[__float_as_uint(v) >> 19], 1u);
    }
  }
  for (long long e = (n8 << 3) + gtid; e < n; e += NT) {
    float pp = preds[e], tt = gts[e];
    dI += (double)(pp * tt);
    dSp += (double)pp;
    dSt += (double)tt;
    float v = poly1_val(pp, tt);
    atomicAdd(&h[__float_as_uint(v) >> 19], 1u);
  }

#pragma unroll
  for (int off = 32; off; off >>= 1) {
    dI += __shfl_down(dI, off, 64);
    dSp += __shfl_down(dSp, off, 64);
    dSt += __shfl_down(dSt, off, 64);
  }
  if ((threadIdx.x & 63) == 0) {
    int w = threadIdx.x >> 6;
    wred[w][0] = dI; wred[w][1] = dSp; wred[w][2] = dSt;
  }
  __syncthreads();
  if (threadIdx.x == 0) {
    double a = 0, b = 0, c = 0;
#pragma unroll
    for (int w = 0; w < 4; ++w) { a += wred[w][0]; b += wred[w][1]; c += wred[w][2]; }
    blockSums[blockIdx.x * 3 + 0] = a;
    blockSums[blockIdx.x * 3 + 1] = b;
    blockSums[blockIdx.x * 3 + 2] = c;
  }

  unsigned int* dst = hist1R + (size_t)(blockIdx.x & (NREP1 - 1)) * NBINS;
  for (int i = threadIdx.x; i < NBINS; i += 256) {
    unsigned c2 = h[i];
    if (c2) atomicAdd(&dst[i], c2);
  }
}

// ---------------- pass 2: embedded select1 + sum>b1 + refine in b1 ---------
__global__ void __launch_bounds__(256, 6) pass2_kernel(
    const float* __restrict__ preds, const float* __restrict__ gts,
    long long n, unsigned int K, const unsigned int* __restrict__ hist1R,
    double* __restrict__ blockSgt, unsigned int* __restrict__ hist2R,
    float* __restrict__ sum2R) {
  __shared__ unsigned int hp[NBINS / 2];  // u16-packed fine counts (8KB)
  __shared__ float s[NBINS];              // fine f32 sums (16KB)
  __shared__ unsigned int chunk[256];
  __shared__ double wred[4];
  __shared__ unsigned int sb1;

  const int t = threadIdx.x;

  // ---- select1 (redundant per block): bins [t*16, t*16+16) ----
  {
    unsigned loc[16];
    unsigned tot = 0;
#pragma unroll
    for (int q = 0; q < 4; ++q) {
      uint4 acc = {0u, 0u, 0u, 0u};
      for (int r = 0; r < NREP1; ++r) {
        uint4 v = *(const uint4*)&hist1R[(size_t)r * NBINS + t * 16 + q * 4];
        acc.x += v.x; acc.y += v.y; acc.z += v.z; acc.w += v.w;
      }
      loc[q * 4 + 0] = acc.x; loc[q * 4 + 1] = acc.y;
      loc[q * 4 + 2] = acc.z; loc[q * 4 + 3] = acc.w;
      tot += acc.x + acc.y + acc.z + acc.w;
    }
    chunk[t] = tot;
    __syncthreads();
    for (int off = 1; off < 256; off <<= 1) {  // suffix scan
      unsigned add = (t + off < 256) ? chunk[t + off] : 0u;
      __syncthreads();
      chunk[t] += add;
      __syncthreads();
    }
    unsigned cum = (t < 255) ? chunk[t + 1] : 0u;  // count of bins > t*16+15
    for (int j = 15; j >= 0; --j) {
      unsigned nc = cum + loc[j];
      if (cum < K && nc >= K) sb1 = (unsigned)(t * 16 + j);
      cum = nc;
    }
  }
  for (int i = t; i < NBINS / 2; i += 256) hp[i] = 0u;
  for (int i = t; i < NBINS; i += 256) s[i] = 0.f;
  __syncthreads();  // publishes sb1 and zeroed LDS
  const unsigned b1v = sb1;

  double sgt = 0.0;
  const long long n8 = n >> 3;
  const float4* p4 = (const float4*)preds;
  const float4* t4 = (const float4*)gts;
  const long long NT = (long long)G2 * 256;
  const long long gtid = (long long)blockIdx.x * 256 + t;

#define PROC2(pp, tt)                                        \
  do {                                                       \
    float _v = poly1_val((pp), (tt));                        \
    unsigned _u = __float_as_uint(_v);                       \
    unsigned _b = _u >> 19;                                  \
    if (_b > b1v) {                                          \
      sgt += (double)_v;                                     \
    } else if (_b == b1v) {                                  \
      unsigned _k = (_u >> 7) & 0xFFFu;                      \
      atomicAdd(&hp[_k >> 1], (_k & 1u) ? 0x10000u : 1u);    \
      atomicAdd(&s[_k], _v);                                 \
    }                                                        \
  } while (0)

  for (long long i = gtid; i < n8; i += NT) {
    long long j = i << 1;
    float4 pa = p4[j], pb = p4[j + 1];
    float4 ta = t4[j], tb = t4[j + 1];
    PROC2(pa.x, ta.x); PROC2(pa.y, ta.y); PROC2(pa.z, ta.z); PROC2(pa.w, ta.w);
    PROC2(pb.x, tb.x); PROC2(pb.y, tb.y); PROC2(pb.z, tb.z); PROC2(pb.w, tb.w);
  }
  for (long long e = (n8 << 3) + gtid; e < n; e += NT) PROC2(preds[e], gts[e]);
#undef PROC2

#pragma unroll
  for (int off = 32; off; off >>= 1) sgt += __shfl_down(sgt, off, 64);
  if ((t & 63) == 0) wred[t >> 6] = sgt;
  __syncthreads();
  if (t == 0) blockSgt[blockIdx.x] = wred[0] + wred[1] + wred[2] + wred[3];

  unsigned int* hd = hist2R + (size_t)(blockIdx.x & (NREP2 - 1)) * NBINS;
  float* sd = sum2R + (size_t)(blockIdx.x & (NREP2 - 1)) * NBINS;
  for (int i = t; i < NBINS / 2; i += 256) {
    unsigned pw = hp[i];
    unsigned c0 = pw & 0xFFFFu, c1 = pw >> 16;
    if (c0) atomicAdd(&hd[2 * i + 0], c0);
    if (c1) atomicAdd(&hd[2 * i + 1], c1);
  }
  for (int i = t; i < NBINS; i += 256) {
    float sv = s[i];
    if (sv != 0.f) atomicAdd(&sd[i], sv);
  }
}

// ---------------- select1(for r) + select2 + finalize, one block -----------
__global__ void __launch_bounds__(1024) sel2fin_kernel(
    const unsigned int* __restrict__ hist1R,
    const unsigned int* __restrict__ hist2R, const float* __restrict__ sum2R,
    const double* __restrict__ blockSums, const double* __restrict__ blockSgt,
    float* __restrict__ out, unsigned int K) {
  __shared__ unsigned int chunk[1024];
  __shared__ double redsA[16], redsB[16], redsC[16];
  __shared__ double wred[16][4];
  __shared__ unsigned int sr1, sb2, sr2;
  const int t = threadIdx.x;

  // ---- re-derive b1, r from hist1R (bins t*4..t*4+3) ----
  unsigned b1loc[4];
  {
    uint4 acc = {0u, 0u, 0u, 0u};
    for (int r = 0; r < NREP1; ++r) {
      uint4 v = *(const uint4*)&hist1R[(size_t)r * NBINS + t * 4];
      acc.x += v.x; acc.y += v.y; acc.z += v.z; acc.w += v.w;
    }
    b1loc[0] = acc.x; b1loc[1] = acc.y; b1loc[2] = acc.z; b1loc[3] = acc.w;
    chunk[t] = acc.x + acc.y + acc.z + acc.w;
    __syncthreads();
    for (int off = 1; off < 1024; off <<= 1) {
      unsigned add = (t + off < 1024) ? chunk[t + off] : 0u;
      __syncthreads();
      chunk[t] += add;
      __syncthreads();
    }
    unsigned cum = (t < 1023) ? chunk[t + 1] : 0u;
    for (int j = 3; j >= 0; --j) {
      unsigned nc = cum + b1loc[j];
      if (cum < K && nc >= K) sr1 = K - cum;  // b1 itself not needed here
      cum = nc;
    }
    __syncthreads();
  }
  const unsigned K2 = sr1;  // remaining count needed from bucket b1 (>= 1)

  // ---- select2 within bucket b1 (fine bins t*4..t*4+3) ----
  unsigned hl[4];
  float sl[4];
  {
    uint4 hacc = {0u, 0u, 0u, 0u};
    float4 sacc = {0.f, 0.f, 0.f, 0.f};
    for (int r = 0; r < NREP2; ++r) {
      uint4 hv = *(const uint4*)&hist2R[(size_t)r * NBINS + t * 4];
      float4 sv = *(const float4*)&sum2R[(size_t)r * NBINS + t * 4];
      hacc.x += hv.x; hacc.y += hv.y; hacc.z += hv.z; hacc.w += hv.w;
      sacc.x += sv.x; sacc.y += sv.y; sacc.z += sv.z; sacc.w += sv.w;
    }
    hl[0] = hacc.x; hl[1] = hacc.y; hl[2] = hacc.z; hl[3] = hacc.w;
    sl[0] = sacc.x; sl[1] = sacc.y; sl[2] = sacc.z; sl[3] = sacc.w;
    chunk[t] = hacc.x + hacc.y + hacc.z + hacc.w;
    __syncthreads();
    for (int off = 1; off < 1024; off <<= 1) {
      unsigned add = (t + off < 1024) ? chunk[t + off] : 0u;
      __syncthreads();
      chunk[t] += add;
      __syncthreads();
    }
    unsigned cum = (t < 1023) ? chunk[t + 1] : 0u;
    for (int j = 3; j >= 0; --j) {
      unsigned nc = cum + hl[j];
      if (cum < K2 && nc >= K2) { sb2 = (unsigned)(t * 4 + j); sr2 = K2 - cum; }
      cum = nc;
    }
    __syncthreads();
  }
  const unsigned b2 = sb2, r2 = sr2;

  // exact sum of sub-buckets strictly above b2; b2's own count/sum
  double loc = 0.0, b2s = 0.0, b2c = 0.0;
#pragma unroll
  for (int j = 0; j < 4; ++j) {
    int bin = t * 4 + j;
    if (bin > (int)b2) loc += (double)sl[j];
    if (bin == (int)b2) { b2s = (double)sl[j]; b2c = (double)hl[j]; }
  }
#pragma unroll
  for (int off = 32; off; off >>= 1) {
    loc += __shfl_down(loc, off, 64);
    b2s += __shfl_down(b2s, off, 64);
    b2c += __shfl_down(b2c, off, 64);
  }
  if ((t & 63) == 0) { int w = t >> 6; redsA[w] = loc; redsB[w] = b2s; redsC[w] = b2c; }

  // ---- finalize: reduce per-block dice partials + Sgt ----
  double I = 0, Sp = 0, St = 0, Sg = 0;
  for (int i = t; i < G1; i += 1024) {
    I += blockSums[i * 3 + 0];
    Sp += blockSums[i * 3 + 1];
    St += blockSums[i * 3 + 2];
  }
  for (int i = t; i < G2; i += 1024) Sg += blockSgt[i];
#pragma unroll
  for (int off = 32; off; off >>= 1) {
    I += __shfl_down(I, off, 64);
    Sp += __shfl_down(Sp, off, 64);
    St += __shfl_down(St, off, 64);
    Sg += __shfl_down(Sg, off, 64);
  }
  if ((t & 63) == 0) {
    int w = t >> 6;
    wred[w][0] = I; wred[w][1] = Sp; wred[w][2] = St; wred[w][3] = Sg;
  }
  __syncthreads();
  if (t == 0) {
    double S2 = 0, bs = 0, bc = 0;
    double tI = 0, tSp = 0, tSt = 0, tSg = 0;
#pragma unroll
    for (int w = 0; w < 16; ++w) {
      S2 += redsA[w]; bs += redsB[w]; bc += redsC[w];
      tI += wred[w][0]; tSp += wred[w][1]; tSt += wred[w][2]; tSg += wred[w][3];
    }
    // ties in sub-bucket b2 span < 128 ulps: bin average for the r2 remaining
    double topk_extra = S2 + (double)r2 * (bs / bc);
    double dice = 1.0 - (2.0 * tI + 1.0) / (tSp + tSt + 1.0);
    out[0] = (float)(dice + (tSg + topk_extra) / (double)K);
  }
}

extern "C" void kernel_launch(void* const* d_in, const int* in_sizes, int n_in,
                              void* d_out, int out_size, void* d_ws,
                              size_t ws_size, hipStream_t stream) {
  (void)n_in; (void)out_size; (void)ws_size;
  const float* preds = (const float*)d_in[0];
  const float* gts = (const float*)d_in[1];
  long long n = (long long)in_sizes[0];
  unsigned int K = (unsigned int)(n * 10 / 100);  // matches int(N*10/100)

  char* ws = (char*)d_ws;
  double* blockSums = (double*)ws;                     // G1*3*8 = 49152
  double* blockSgt = (double*)(ws + 49152);            // G2*8   = 12288 -> 61440
  unsigned int* hist1R = (unsigned int*)(ws + 61440);  // NREP1*NBINS*4 = 131072
  unsigned int* hist2R = (unsigned int*)(ws + 192512); // NREP2*NBINS*4 = 65536
  float* sum2R = (float*)(ws + 258048);                // 65536 -> end 323584

  // zero only the atomic-accumulated replica region (contiguous, 256KB)
  (void)hipMemsetAsync(ws + 61440, 0, 262144, stream);

  pass1_kernel<<<G1, 256, 0, stream>>>(preds, gts, n, blockSums, hist1R);
  pass2_kernel<<<G2, 256, 0, stream>>>(preds, gts, n, K, hist1R, blockSgt,
                                       hist2R, sum2R);
  sel2fin_kernel<<<1, 1024, 0, stream>>>(hist1R, hist2R, sum2R, blockSums,
                                         blockSgt, (float*)d_out, K);
}